// Round 1
// 406.470 us; speedup vs baseline: 1.0025x; 1.0025x over previous
//
#include <hip/hip_runtime.h>
#include <stdint.h>

// Problem: DynamicVoxelizer. B=8, N=1e6, voxel=0.2, grid (x,y,z)=(512,512,30).
// d_out = FLOAT32 x 88,000,000, concatenated:
//   [0,24M) out_points  [24M,48M) coords_zyx  [48M,56M) idx
//   [56M,80M) offsets   [80M,88M) valid
// History: R3 424us, R5 nt neutral, R6 LDS-staged vec3 stores 407us,
// R7 strided point mapping 407.5us (kernel ~98us; ~309us is harness fills).
// R8 (this): VALU cut.
//  - fp32 divide -> double-reciprocal multiply (exact-division replacement:
//    error window ~2^-52 rel vs the 2^-24 of x*5.0f that flipped boundaries).
//  - stay in float domain: valid via float compares, coord via truncf,
//    no int<->float conversions for coords.
//  - incremental batch-local index (1 magic-div/thread, +256 w/ wrap fix).
// Store structure unchanged from R7 (proven): LDS-staged fx4 coop stores for
// A/B/C regions, direct lane-contiguous dwords for idx/valid.

#define NPB   1000000
#define TOT   8000000
#define BLK   256
#define PPT   4
#define PPB   (BLK * PPT)                 // 1024 points per block
#define NBLK  ((TOT + PPB - 1) / PPB)     // 7813 (last block partial)

typedef float fx4 __attribute__((ext_vector_type(4)));

__global__ __launch_bounds__(256) void voxelize_kernel(
        const float* __restrict__ pts, float* __restrict__ out) {
    __shared__ float lsA[PPB * 3];   // out_points   12 KB
    __shared__ float lsB[PPB * 3];   // coords_zyx   12 KB
    __shared__ float lsC[PPB * 3];   // offsets      12 KB

    const int t = threadIdx.x;
    const uint32_t P0 = (uint32_t)blockIdx.x * PPB;

    // 0.2f == 0x3E4CCCCD == 0.20000000298023223877 exactly.
    // R = correctly-rounded double reciprocal of that value (compile-time).
    // (float)((double)a * R) matches fl32(a / 0.2f) unless the exact quotient
    // is within ~2^-52 relative of an fp32 rounding boundary (measure-zero
    // here; the x*5.0f attempt had a 2^-24-scale window and DID flip).
    const double R = 1.0 / (double)0.2f;

    // Batch-local index: one magic-div per thread, then increment.
    // A block spans 1024 points -> crosses at most one batch boundary.
    const uint32_t n0  = P0 + (uint32_t)t;     // always < TOT (see NBLK)
    const uint32_t b0  = n0 / NPB;             // magic-mul
    const uint32_t ni0 = n0 - b0 * NPB;

#pragma unroll
    for (int j = 0; j < PPT; ++j) {
        int      pb = j * BLK + t;       // point index within block
        uint32_t n  = P0 + pb;           // global point index
        if (n < TOT) {
            uint32_t ni = ni0 + (uint32_t)(j * BLK);
            if (ni >= NPB) ni -= NPB;    // single wrap fix

            // 12B/lane contiguous load (compiler merges to dwordx3)
            const float* pp = pts + (size_t)n * 3;
            float x = pp[0], y = pp[1], z = pp[2];

            bool nn = (x == x) && (y == y) && (z == z);
            float px = nn ? x : 0.0f;
            float py = nn ? y : 0.0f;
            float pz = nn ? z : 0.0f;

            // Exact numpy fp32 sequence: (p - min) computed as fp32 add, then
            // exact-division-equivalent DP multiply, rounded back to fp32.
            float tx = (float)((double)(px + 51.2f) * R);
            float ty = (float)((double)(py + 51.2f) * R);
            float tz = (float)((double)(pz + 3.0f)  * R);

            // Float-domain range check: 0 <= floor(t) < G  <=>  0 <= t < G.
            bool valid = nn && (tx >= 0.0f) && (tx < 512.0f)
                            && (ty >= 0.0f) && (ty < 512.0f)
                            && (tz >= 0.0f) && (tz < 30.0f);

            // truncf == floorf for t >= 0; negative-t lanes are invalid and
            // all their outputs are forced by `valid` selects below.
            float fcx = truncf(tx);
            float fcy = truncf(ty);
            float fcz = truncf(tz);

            // Same fp32 expression shape as reference: ((c*vs) + min) + vs/2
            float ctx = (fcx * 0.2f + (-51.2f)) + 0.1f;
            float cty = (fcy * 0.2f + (-51.2f)) + 0.1f;
            float ctz = (fcz * 0.2f + (-3.0f))  + 0.1f;

            // LDS staging: 12B/lane contiguous, conflict-free
            lsA[3*pb+0] = valid ? px : 0.0f;
            lsA[3*pb+1] = valid ? py : 0.0f;
            lsA[3*pb+2] = valid ? pz : 0.0f;
            lsB[3*pb+0] = valid ? fcz : -1.0f;   // zyx order
            lsB[3*pb+1] = valid ? fcy : -1.0f;
            lsB[3*pb+2] = valid ? fcx : -1.0f;
            lsC[3*pb+0] = valid ? (px - ctx) : 0.0f;
            lsC[3*pb+1] = valid ? (py - cty) : 0.0f;
            lsC[3*pb+2] = valid ? (pz - ctz) : 0.0f;

            // Scalar regions: 4B/lane contiguous dword stores
            out[(size_t)48000000 + n] = valid ? (float)ni : -1.0f;
            out[(size_t)80000000 + n] = valid ? 1.0f : 0.0f;
        }
    }

    __syncthreads();

    // Cooperative lane-contiguous stores: 768 fx4 per region per block.
    size_t f40 = (size_t)blockIdx.x * (PPB * 3 / 4);
#pragma unroll
    for (int i = 0; i < 3; ++i) {
        int    li  = i * BLK + t;          // fx4 index within block
        size_t f4i = f40 + li;
        if (f4i < (size_t)6000000) {       // 24M floats = 6M fx4 per region
            fx4 a = ((const fx4*)lsA)[li];
            fx4 c = ((const fx4*)lsB)[li];
            fx4 o = ((const fx4*)lsC)[li];
            ((fx4*)(out))[f4i]                    = a;
            ((fx4*)(out + (size_t)24000000))[f4i] = c;
            ((fx4*)(out + (size_t)56000000))[f4i] = o;
        }
    }
}

extern "C" void kernel_launch(void* const* d_in, const int* in_sizes, int n_in,
                              void* d_out, int out_size, void* d_ws, size_t ws_size,
                              hipStream_t stream) {
    const float* pts = (const float*)d_in[0];
    float* out = (float*)d_out;
    voxelize_kernel<<<NBLK, BLK, 0, stream>>>(pts, out);
}

// Round 2
// 406.425 us; speedup vs baseline: 1.0026x; 1.0001x over previous
//
#include <hip/hip_runtime.h>
#include <stdint.h>

// Problem: DynamicVoxelizer. B=8, N=1e6, voxel=0.2, grid (x,y,z)=(512,512,30).
// d_out = FLOAT32 x 88,000,000, concatenated:
//   [0,24M) out_points  [24M,48M) coords_zyx  [48M,56M) idx
//   [56M,80M) offsets   [80M,88M) valid
// History: R3 424us, R5 nt neutral, R6 LDS-staged vec3 stores 407us,
// R7 strided point mapping 407.5us, R8 VALU cut (DP-recip div, float-domain
// valid/coords) 406.5us -> NEUTRAL => kernel is memory-system bound, not VALU.
// R9 (this): occupancy. 36KB LDS/block capped residency at 4 blocks/CU
// (16 waves = 50%). PPT 4->2: LDS 18KB/block -> 8 blocks/CU = 32 waves/CU
// (100%, exactly the 2048-thread cap). __launch_bounds__(256,8) pins VGPR<=64.
// Bonus: 8M % 512 == 0 -> no tail guards at all.

#define NPB   1000000
#define TOT   8000000
#define BLK   256
#define PPT   2
#define PPB   (BLK * PPT)                 // 512 points per block
#define NBLK  (TOT / PPB)                 // 15625, exact (no partial block)
#define F4PR  (PPB * 3 / 4)               // 384 fx4 per region per block

typedef float fx4 __attribute__((ext_vector_type(4)));

__global__ __launch_bounds__(256, 8) void voxelize_kernel(
        const float* __restrict__ pts, float* __restrict__ out) {
    __shared__ __attribute__((aligned(16))) float lsA[PPB * 3];  // out_points 6 KB
    __shared__ __attribute__((aligned(16))) float lsB[PPB * 3];  // coords_zyx 6 KB
    __shared__ __attribute__((aligned(16))) float lsC[PPB * 3];  // offsets    6 KB

    const int t = threadIdx.x;
    const uint32_t P0 = (uint32_t)blockIdx.x * PPB;

    // Exact-division replacement: R = correctly-rounded double reciprocal of
    // (double)0.2f. (float)((double)a * R) == fl32(a / 0.2f) except within
    // ~2^-52 rel of an fp32 rounding boundary (verified passing in R8;
    // the x*5.0f fp32-multiply variant had a 2^-24 window and DID flip).
    const double R = 1.0 / (double)0.2f;

    // Batch-local index: one magic-div per thread, then increment.
    // A block spans 512 consecutive points -> crosses at most one batch edge.
    const uint32_t n0  = P0 + (uint32_t)t;
    const uint32_t b0  = n0 / NPB;             // magic-mul
    const uint32_t ni0 = n0 - b0 * NPB;

#pragma unroll
    for (int j = 0; j < PPT; ++j) {
        int      pb = j * BLK + t;       // point index within block
        uint32_t n  = P0 + pb;           // global point index (< TOT always)
        uint32_t ni = ni0 + (uint32_t)(j * BLK);
        if (ni >= NPB) ni -= NPB;        // single wrap fix

        // 12B/lane contiguous load (compiler merges to dwordx3)
        const float* pp = pts + (size_t)n * 3;
        float x = pp[0], y = pp[1], z = pp[2];

        bool nn = (x == x) && (y == y) && (z == z);
        float px = nn ? x : 0.0f;
        float py = nn ? y : 0.0f;
        float pz = nn ? z : 0.0f;

        // Exact numpy fp32 sequence: fp32 add, exact-division DP multiply,
        // round back to fp32.
        float tx = (float)((double)(px + 51.2f) * R);
        float ty = (float)((double)(py + 51.2f) * R);
        float tz = (float)((double)(pz + 3.0f)  * R);

        // Float-domain range check: 0 <= floor(t) < G  <=>  0 <= t < G.
        bool valid = nn && (tx >= 0.0f) && (tx < 512.0f)
                        && (ty >= 0.0f) && (ty < 512.0f)
                        && (tz >= 0.0f) && (tz < 30.0f);

        // truncf == floorf for t >= 0; negative-t lanes are invalid and all
        // their outputs are forced by the `valid` selects below.
        float fcx = truncf(tx);
        float fcy = truncf(ty);
        float fcz = truncf(tz);

        // Same fp32 expression shape as reference: ((c*vs) + min) + vs/2
        float ctx = (fcx * 0.2f + (-51.2f)) + 0.1f;
        float cty = (fcy * 0.2f + (-51.2f)) + 0.1f;
        float ctz = (fcz * 0.2f + (-3.0f))  + 0.1f;

        // LDS staging: 12B/lane contiguous, conflict-free
        lsA[3*pb+0] = valid ? px : 0.0f;
        lsA[3*pb+1] = valid ? py : 0.0f;
        lsA[3*pb+2] = valid ? pz : 0.0f;
        lsB[3*pb+0] = valid ? fcz : -1.0f;   // zyx order
        lsB[3*pb+1] = valid ? fcy : -1.0f;
        lsB[3*pb+2] = valid ? fcx : -1.0f;
        lsC[3*pb+0] = valid ? (px - ctx) : 0.0f;
        lsC[3*pb+1] = valid ? (py - cty) : 0.0f;
        lsC[3*pb+2] = valid ? (pz - ctz) : 0.0f;

        // Scalar regions: 4B/lane contiguous dword stores
        out[(size_t)48000000 + n] = valid ? (float)ni : -1.0f;
        out[(size_t)80000000 + n] = valid ? 1.0f : 0.0f;
    }

    __syncthreads();

    // Cooperative lane-contiguous stores: 384 fx4 per region per block
    // (iter 0: all 256 lanes; iter 1: lanes 0..127).
    size_t f40 = (size_t)blockIdx.x * F4PR;
#pragma unroll
    for (int i = 0; i < 2; ++i) {
        int li = i * BLK + t;              // fx4 index within block
        if (li < F4PR) {
            size_t f4i = f40 + li;
            fx4 a = ((const fx4*)lsA)[li];
            fx4 c = ((const fx4*)lsB)[li];
            fx4 o = ((const fx4*)lsC)[li];
            ((fx4*)(out))[f4i]                    = a;
            ((fx4*)(out + (size_t)24000000))[f4i] = c;
            ((fx4*)(out + (size_t)56000000))[f4i] = o;
        }
    }
}

extern "C" void kernel_launch(void* const* d_in, const int* in_sizes, int n_in,
                              void* d_out, int out_size, void* d_ws, size_t ws_size,
                              hipStream_t stream) {
    const float* pts = (const float*)d_in[0];
    float* out = (float*)d_out;
    voxelize_kernel<<<NBLK, BLK, 0, stream>>>(pts, out);
}